// Round 1
// baseline (157.945 us; speedup 1.0000x reference)
//
#include <hip/hip_runtime.h>

#define NB 16
#define NG 20
#define NA 8400

__device__ __forceinline__ float waveMax(float v) {
#pragma unroll
    for (int o = 32; o > 0; o >>= 1) v = fmaxf(v, __shfl_down(v, o));
    return v;
}
__device__ __forceinline__ double waveSum(double v) {
#pragma unroll
    for (int o = 32; o > 0; o >>= 1) v += __shfl_down(v, o);
    return v;
}

__global__ __launch_bounds__(256) void kd_main(
    const float* __restrict__ st0, const float* __restrict__ st1, const float* __restrict__ st2,
    const float* __restrict__ te0, const float* __restrict__ te1, const float* __restrict__ te2,
    const float* __restrict__ labels, double* __restrict__ acc)
{
    __shared__ float  s_st[NA];
    __shared__ float  s_te[NA];
    __shared__ float  shf[8];
    __shared__ double shd[12];

    const int tid = threadIdx.x;
    const int blk = blockIdx.x;
    const int b = blk / NG;
    const int g = blk - b * NG;

    const float* lab = labels + (size_t)(b * NG + g) * 5;
    const float gcx = lab[1], gcy = lab[2], gw = lab[3], gh = lab[4];
    const float gl  = gcx - 0.5f * gw, gr  = gcx + 0.5f * gw;
    const float gtp = gcy - 0.5f * gh, gbt = gcy + 0.5f * gh;
    const float area_g = gw * gh;

    float m_st = -3e38f, m_te = -3e38f;

    // Pass 1: decode + IoU + mask; stash masked IoUs in LDS, track maxes.
    for (int i = tid; i < NA; i += 256) {
        int ax, ay, loc, S; float stride; const float* sp; const float* tp;
        if (i < 6400)      { loc = i;        ay = loc / 80; ax = loc - ay * 80; stride =  8.f; S = 6400; sp = st0 + (size_t)b * 4 * 6400; tp = te0 + (size_t)b * 4 * 6400; }
        else if (i < 8000) { loc = i - 6400; ay = loc / 40; ax = loc - ay * 40; stride = 16.f; S = 1600; sp = st1 + (size_t)b * 4 * 1600; tp = te1 + (size_t)b * 4 * 1600; }
        else               { loc = i - 8000; ay = loc / 20; ax = loc - ay * 20; stride = 32.f; S =  400; sp = st2 + (size_t)b * 4 *  400; tp = te2 + (size_t)b * 4 *  400; }

        const float ccx = (ax + 0.5f) * stride;
        const float ccy = (ay + 0.5f) * stride;
        const bool mask = (ccx > gl) && (ccy > gtp) && (ccx < gr) && (ccy < gbt);

        float vst = -3e38f, vte = -3e38f;
        if (mask) {
            // student box
            {
                float r0 = sp[loc], r1 = sp[S + loc], r2 = sp[2 * S + loc], r3 = sp[3 * S + loc];
                float px = (r0 + (float)ax) * stride, py = (r1 + (float)ay) * stride;
                float pw = expf(r2) * stride,         ph = expf(r3) * stride;
                float tlx = fmaxf(gl,  px - 0.5f * pw);
                float tly = fmaxf(gtp, py - 0.5f * ph);
                float brx = fminf(gr,  px + 0.5f * pw);
                float bry = fminf(gbt, py + 0.5f * ph);
                float ai = ((tlx < brx) && (tly < bry)) ? (brx - tlx) * (bry - tly) : 0.f;
                vst = ai / (area_g + pw * ph - ai + 1e-16f);
            }
            // teacher box
            {
                float r0 = tp[loc], r1 = tp[S + loc], r2 = tp[2 * S + loc], r3 = tp[3 * S + loc];
                float px = (r0 + (float)ax) * stride, py = (r1 + (float)ay) * stride;
                float pw = expf(r2) * stride,         ph = expf(r3) * stride;
                float tlx = fmaxf(gl,  px - 0.5f * pw);
                float tly = fmaxf(gtp, py - 0.5f * ph);
                float brx = fminf(gr,  px + 0.5f * pw);
                float bry = fminf(gbt, py + 0.5f * ph);
                float ai = ((tlx < brx) && (tly < bry)) ? (brx - tlx) * (bry - tly) : 0.f;
                vte = ai / (area_g + pw * ph - ai + 1e-16f);
            }
            m_st = fmaxf(m_st, vst);
            m_te = fmaxf(m_te, vte);
        }
        s_st[i] = vst;
        s_te[i] = vte;
    }
    __syncthreads();

    // Block max reduction (st & te together).
    m_st = waveMax(m_st); m_te = waveMax(m_te);
    const int w = tid >> 6;
    if ((tid & 63) == 0) { shf[w] = m_st; shf[4 + w] = m_te; }
    __syncthreads();
    if (tid == 0) {
        shf[0] = fmaxf(fmaxf(shf[0], shf[1]), fmaxf(shf[2], shf[3]));
        shf[4] = fmaxf(fmaxf(shf[4], shf[5]), fmaxf(shf[6], shf[7]));
    }
    __syncthreads();
    m_st = shf[0]; m_te = shf[4];

    // Pass 2: masked exp-sums (double accumulation).
    double s_sum = 0.0, t_sum = 0.0;
    for (int i = tid; i < NA; i += 256) {
        float v = s_st[i];
        if (v > -1e38f) {
            s_sum += (double)expf(v - m_st);
            t_sum += (double)expf(s_te[i] - m_te);
        }
    }
    s_sum = waveSum(s_sum); t_sum = waveSum(t_sum);
    if ((tid & 63) == 0) { shd[w] = s_sum; shd[4 + w] = t_sum; }
    __syncthreads();
    if (tid == 0) {
        shd[0] = shd[0] + shd[1] + shd[2] + shd[3];
        shd[4] = shd[4] + shd[5] + shd[6] + shd[7];
    }
    __syncthreads();
    const double ls = log(shd[0]);   // only consumed for masked entries
    const double lt = log(shd[4]);

    // Pass 3: KL sum.
    double kl = 0.0;
    for (int i = tid; i < NA; i += 256) {
        float v = s_st[i];
        if (v > -1e38f) {
            float  u    = s_te[i];
            double lpte = (double)(u - m_te) - lt;   // log te_p  (>= -1 - log(8400), clip(1e-30) inactive)
            double p    = exp(lpte);
            double lpst = (double)(v - m_st) - ls;   // st log_softmax
            kl += p * (lpte - lpst);
        }
    }
    kl = waveSum(kl);
    if ((tid & 63) == 0) shd[8 + w] = kl;
    __syncthreads();
    if (tid == 0) {
        double tot = shd[8] + shd[9] + shd[10] + shd[11];
        atomicAdd(acc, tot * (1.0 / (double)(NB * NG)));
    }
}

__global__ void kd_final(const double* __restrict__ acc, float* __restrict__ out) {
    out[0] = (float)acc[0];
}

extern "C" void kernel_launch(void* const* d_in, const int* in_sizes, int n_in,
                              void* d_out, int out_size, void* d_ws, size_t ws_size,
                              hipStream_t stream) {
    const float* st0 = (const float*)d_in[0];
    const float* st1 = (const float*)d_in[3];
    const float* st2 = (const float*)d_in[6];
    const float* te0 = (const float*)d_in[9];
    const float* te1 = (const float*)d_in[12];
    const float* te2 = (const float*)d_in[15];
    const float* lab = (const float*)d_in[18];
    double* acc = (double*)d_ws;

    hipMemsetAsync(acc, 0, sizeof(double), stream);
    kd_main<<<NB * NG, 256, 0, stream>>>(st0, st1, st2, te0, te1, te2, lab, acc);
    kd_final<<<1, 1, 0, stream>>>(acc, (float*)d_out);
}

// Round 2
// 138.578 us; speedup vs baseline: 1.1398x; 1.1398x over previous
//
#include <hip/hip_runtime.h>

#define NGT 20

__device__ __forceinline__ double waveSum64(double v) {
#pragma unroll
    for (int o = 32; o > 0; o >>= 1) v += __shfl_down(v, o);
    return v;
}

__global__ __launch_bounds__(256) void kd_fused(
    const float* __restrict__ st0, const float* __restrict__ st1, const float* __restrict__ st2,
    const float* __restrict__ te0, const float* __restrict__ te1, const float* __restrict__ te2,
    const float* __restrict__ labels, float* __restrict__ out)
{
    __shared__ double shd[12];

    const int tid = threadIdx.x;
    const int blk = blockIdx.x;          // blk = b*NGT + g
    const int b   = blk / NGT;

    const float* lab = labels + (size_t)blk * 5;
    const float gcx = lab[1], gcy = lab[2], gw = lab[3], gh = lab[4];
    const float gl  = gcx - 0.5f * gw, gr  = gcx + 0.5f * gw;
    const float gtp = gcy - 0.5f * gh, gbt = gcy + 0.5f * gh;
    const float area_g = gw * gh;

    // Conservative masked-cell rectangles per level (exact float mask re-checked per cell).
    int X0[3], Y0[3], RW[3], CNT[3];
    {
        const float ss[3] = {8.f, 16.f, 32.f};
        const int   WW[3] = {80, 40, 20};
#pragma unroll
        for (int l = 0; l < 3; ++l) {
            float s = ss[l]; int W = WW[l];
            int x0 = (int)floorf(gl  / s - 0.5f) - 1; if (x0 < 0) x0 = 0;
            int x1 = (int)ceilf (gr  / s - 0.5f) + 1; if (x1 > W - 1) x1 = W - 1;
            int y0 = (int)floorf(gtp / s - 0.5f) - 1; if (y0 < 0) y0 = 0;
            int y1 = (int)ceilf (gbt / s - 0.5f) + 1; if (y1 > W - 1) y1 = W - 1;
            int rw = x1 - x0 + 1; if (rw < 0) rw = 0;
            int rh = y1 - y0 + 1; if (rh < 0) rh = 0;
            X0[l] = x0; Y0[l] = y0; RW[l] = rw; CNT[l] = rw * rh;
        }
    }
    const int c0 = CNT[0], c01 = CNT[0] + CNT[1], tot = c01 + CNT[2];

    double ss_d = 0.0, st_d = 0.0, tt_d = 0.0;

    for (int j = tid; j < tot; j += 256) {
        int loc, x0, y0, rw, W, S; float s; const float* sp; const float* tp;
        if (j < c0) {
            loc = j;      x0 = X0[0]; y0 = Y0[0]; rw = RW[0]; W = 80; S = 6400; s = 8.f;
            sp = st0 + (size_t)b * 4 * 6400; tp = te0 + (size_t)b * 4 * 6400;
        } else if (j < c01) {
            loc = j - c0; x0 = X0[1]; y0 = Y0[1]; rw = RW[1]; W = 40; S = 1600; s = 16.f;
            sp = st1 + (size_t)b * 4 * 1600; tp = te1 + (size_t)b * 4 * 1600;
        } else {
            loc = j - c01; x0 = X0[2]; y0 = Y0[2]; rw = RW[2]; W = 20; S = 400; s = 32.f;
            sp = st2 + (size_t)b * 4 * 400;  tp = te2 + (size_t)b * 4 * 400;
        }
        const int ry = loc / rw;
        const int ax = x0 + (loc - ry * rw);
        const int ay = y0 + ry;

        const float ccx = (ax + 0.5f) * s;
        const float ccy = (ay + 0.5f) * s;
        if ((ccx > gl) & (ccx < gr) & (ccy > gtp) & (ccy < gbt)) {
            const int p = ay * W + ax;
            float vst, vte;
            {
                float r0 = sp[p], r1 = sp[S + p], r2 = sp[2 * S + p], r3 = sp[3 * S + p];
                float px = (r0 + (float)ax) * s, py = (r1 + (float)ay) * s;
                float pw = expf(r2) * s,         ph = expf(r3) * s;
                float tlx = fmaxf(gl,  px - 0.5f * pw);
                float tly = fmaxf(gtp, py - 0.5f * ph);
                float brx = fminf(gr,  px + 0.5f * pw);
                float bry = fminf(gbt, py + 0.5f * ph);
                float ai = ((tlx < brx) && (tly < bry)) ? (brx - tlx) * (bry - tly) : 0.f;
                vst = ai / (area_g + pw * ph - ai + 1e-16f);
            }
            {
                float r0 = tp[p], r1 = tp[S + p], r2 = tp[2 * S + p], r3 = tp[3 * S + p];
                float px = (r0 + (float)ax) * s, py = (r1 + (float)ay) * s;
                float pw = expf(r2) * s,         ph = expf(r3) * s;
                float tlx = fmaxf(gl,  px - 0.5f * pw);
                float tly = fmaxf(gtp, py - 0.5f * ph);
                float brx = fminf(gr,  px + 0.5f * pw);
                float bry = fminf(gbt, py + 0.5f * ph);
                float ai = ((tlx < brx) && (tly < bry)) ? (brx - tlx) * (bry - tly) : 0.f;
                vte = ai / (area_g + pw * ph - ai + 1e-16f);
            }
            // Fixed shift of 1.0 (IoU <= 1): softmax is shift-invariant.
            const float es = expf(vst - 1.f);
            const float et = expf(vte - 1.f);
            ss_d += (double)es;
            st_d += (double)et;
            tt_d += (double)(et * (vte - vst));
        }
    }

    // Reduce 3 doubles across the block (4 waves).
    ss_d = waveSum64(ss_d); st_d = waveSum64(st_d); tt_d = waveSum64(tt_d);
    const int w = tid >> 6;
    if ((tid & 63) == 0) { shd[w] = ss_d; shd[4 + w] = st_d; shd[8 + w] = tt_d; }
    __syncthreads();
    if (tid == 0) {
        const double Ss = shd[0] + shd[1] + shd[2] + shd[3];
        const double St = shd[4] + shd[5] + shd[6] + shd[7];
        const double Tt = shd[8] + shd[9] + shd[10] + shd[11];
        if (St > 0.0) {
            // KL = T/S_t + log(S_s) - log(S_t); per-pair weight 1/(B*L) = 1/320.
            const double kl = Tt / St + log(Ss) - log(St);
            atomicAdd(out, (float)(kl * (1.0 / 320.0)));
        }
    }
}

extern "C" void kernel_launch(void* const* d_in, const int* in_sizes, int n_in,
                              void* d_out, int out_size, void* d_ws, size_t ws_size,
                              hipStream_t stream) {
    const float* st0 = (const float*)d_in[0];
    const float* st1 = (const float*)d_in[3];
    const float* st2 = (const float*)d_in[6];
    const float* te0 = (const float*)d_in[9];
    const float* te1 = (const float*)d_in[12];
    const float* te2 = (const float*)d_in[15];
    const float* lab = (const float*)d_in[18];

    kd_fused<<<16 * NGT, 256, 0, stream>>>(st0, st1, st2, te0, te1, te2, lab, (float*)d_out);
}